// Round 7
// baseline (629.490 us; speedup 1.0000x reference)
//
#include <hip/hip_runtime.h>
#include <hip/hip_bf16.h>

#define THREADS 256

typedef __attribute__((ext_vector_type(4))) float f32x4;
typedef __attribute__((ext_vector_type(8))) short short8;
typedef __attribute__((ext_vector_type(4))) unsigned short u16x4;

__device__ inline unsigned short f2bf(float f) {
    unsigned int u = __builtin_bit_cast(unsigned int, f);
    unsigned int r = (u + 0x7FFFu + ((u >> 16) & 1u)) >> 16;
    return (unsigned short)r;
}
__device__ inline float bf2f(unsigned short h) {
    unsigned int u = ((unsigned int)h) << 16;
    return __builtin_bit_cast(float, u);
}

#if defined(__has_builtin)
#if __has_builtin(__builtin_amdgcn_global_load_lds)
#define HAVE_GLOAD_LDS 1
#endif
#endif

template <typename T>
__device__ __forceinline__ void nt_store(const T& v, T* p) {
#if defined(__has_builtin) && __has_builtin(__builtin_nontemporal_store)
    __builtin_nontemporal_store(v, p);
#else
    *p = v;
#endif
}

// One 16B chunk per lane; lds base must be wave-uniform (HW: base + lane*16).
__device__ __forceinline__ void async_copy16(const void* g, void* lds) {
#ifdef HAVE_GLOAD_LDS
    __builtin_amdgcn_global_load_lds((const __attribute__((address_space(1))) void*)g,
                                     (__attribute__((address_space(3))) void*)lds, 16, 0, 0);
#else
    int lane = threadIdx.x & 63;
    *(short8*)((short*)lds + lane * 8) = *(const short8*)g;
#endif
}

// ---------------- graph preprocessing ----------------

__global__ __launch_bounds__(256) void init_cnt_kernel(int* cnt, int n) {
    int i = blockIdx.x * blockDim.x + threadIdx.x;
    if (i < n) cnt[i] = 1;   // self loop
}

__global__ __launch_bounds__(256) void count_edges_kernel(const int* ei, int* cnt, int E) {
    int e = blockIdx.x * blockDim.x + threadIdx.x;
    if (e < E) atomicAdd(&cnt[ei[E + e]], 1);   // dst row
}

// single-block exclusive scan: 1024 threads, chunked
__global__ __launch_bounds__(1024) void scan_kernel(const int* cnt, int* row_ptr, int n) {
    __shared__ int sh[1024];
    int chunk = (n + 1023) >> 10;
    int beg = (int)threadIdx.x * chunk;
    int end = min(beg + chunk, n);
    int s = 0;
    for (int i = beg; i < end; ++i) s += cnt[i];
    sh[threadIdx.x] = s;
    __syncthreads();
    for (int off = 1; off < 1024; off <<= 1) {
        int t = (threadIdx.x >= (unsigned)off) ? sh[threadIdx.x - off] : 0;
        __syncthreads();
        sh[threadIdx.x] += t;
        __syncthreads();
    }
    int run = sh[threadIdx.x] - s;   // exclusive prefix
    for (int i = beg; i < end; ++i) { row_ptr[i] = run; run += cnt[i]; }
    if (threadIdx.x == 1023) row_ptr[n] = run;
}

// dinv + self-fill + cursor init in one pass
__global__ __launch_bounds__(256) void prep_fused_kernel(const int* cnt, const int* row_ptr,
                                                         int* cursor, float* dinv,
                                                         int* src_sorted, int n) {
    int i = blockIdx.x * blockDim.x + threadIdx.x;
    if (i < n) {
        dinv[i] = rsqrtf((float)cnt[i]);
        int p = row_ptr[i];
        src_sorted[p] = i;     // self loop first (deterministic slot)
        cursor[i] = p + 1;
    }
}

__global__ __launch_bounds__(256) void fill_edges_kernel(const int* ei, int* cursor, int* src_sorted, int E) {
    int e = blockIdx.x * blockDim.x + threadIdx.x;
    if (e < E) {
        int s = ei[e];
        int d = ei[E + e];
        int pos = atomicAdd(&cursor[d], 1);
        src_sorted[pos] = s;
    }
}

// ---------------- split-bf16 conversion ----------------
// x -> [hi | lo]  (row length 2F)
__global__ __launch_bounds__(256) void convert_x_kernel(const float* __restrict__ x,
                                                        unsigned short* __restrict__ xs,
                                                        int n, int F) {
    long idx = (long)blockIdx.x * 256 + threadIdx.x;
    long total = (long)n * (F / 4);
    if (idx >= total) return;
    int row = (int)(idx / (F / 4));
    int c4 = (int)(idx % (F / 4)) * 4;
    f32x4 v = *(const f32x4*)&x[(long)row * F + c4];
    u16x4 hi, lo;
#pragma unroll
    for (int j = 0; j < 4; ++j) {
        hi[j] = f2bf(v[j]);
        lo[j] = f2bf(v[j] - bf2f(hi[j]));
    }
    unsigned short* base = xs + (long)row * 2 * F;
    *(u16x4*)&base[c4] = hi;
    *(u16x4*)&base[F + c4] = lo;
}

// W [K,N] f32 -> Wt [N, 3K] bf16 transposed: rows of B' = [hi; hi; lo]
__global__ __launch_bounds__(256) void convert_w_kernel(const float* __restrict__ W,
                                                        unsigned short* __restrict__ Wt,
                                                        int K, int N) {
    int idx = blockIdx.x * 256 + threadIdx.x;
    if (idx >= K * N) return;
    int k = idx / N, n = idx % N;
    float v = W[(long)k * N + n];
    unsigned short hi = f2bf(v);
    unsigned short lo = f2bf(v - bf2f(hi));
    unsigned short* base = Wt + (long)n * 3 * K;
    base[k] = hi;
    base[K + k] = hi;
    base[2 * K + k] = lo;
}

// ---------------- MFMA bf16 GEMM: C[M,N] = A'[M,Kp] * Bt[N,Kp]^T, epilogue *dinv[row] ----------------
// BM=64, BN=N (one column block, A read exactly once), BK=64, 256 threads = 4 waves.
// A stored [hi|lo] (row len KA=2F); logical third segment [2F,3F) remapped to hi.
// LDS fragment-chunk layout -> conflict-free b128, global_load_lds 16B staging.
template <int BN>
__global__ __launch_bounds__(256) void gemm_bf16_kernel(const unsigned short* __restrict__ A,
                                                        const unsigned short* __restrict__ Bt,
                                                        const float* __restrict__ dinv,
                                                        float* __restrict__ C,
                                                        int M, int KA, int Kp, int N) {
    constexpr int WAVES_N = BN / 64;
    constexpr int WAVES_M = 4 / WAVES_N;
    constexpr int MI = 4 / WAVES_M;       // 16-row tiles per wave (BM=64)
    constexpr int AITERS = 2;             // 512 A-chunks / 256 threads
    constexpr int BITERS = BN / 32;       // (BN/16)*2*64 / 256
    __shared__ short As[64 * 64];
    __shared__ short Bs[BN * 64];
    const int tid = threadIdx.x;
    const int m0 = blockIdx.x * 64;
    const int wave = tid >> 6, l = tid & 63;
    const int wn = wave / WAVES_M, wm = wave % WAVES_M;
    const int lr = l & 15, lg = l >> 4;
    f32x4 acc[MI][4] = {};
    for (int k0 = 0; k0 < Kp; k0 += 64) {
#pragma unroll
        for (int it = 0; it < AITERS; ++it) {
            int chunk = it * 256 + tid;
            int mi = chunk >> 7, ks = (chunk >> 6) & 1, cl = chunk & 63;
            long row = m0 + mi * 16 + (cl & 15);
            int gk = k0 + ks * 32 + ((cl >> 4) << 3);
            if (gk >= KA) gk -= KA;       // [hi|lo|hi] logical from [hi|lo] storage
            async_copy16(&A[row * KA + gk], &As[(size_t)(it * 256 + (tid & ~63)) * 8]);
        }
#pragma unroll
        for (int it = 0; it < BITERS; ++it) {
            int chunk = it * 256 + tid;
            int ni = chunk >> 7, ks = (chunk >> 6) & 1, cl = chunk & 63;
            long col = ni * 16 + (cl & 15);
            int gk = k0 + ks * 32 + ((cl >> 4) << 3);
            async_copy16(&Bt[col * Kp + gk], &Bs[(size_t)(it * 256 + (tid & ~63)) * 8]);
        }
        __syncthreads();
#pragma unroll
        for (int ks = 0; ks < 2; ++ks) {
            short8 a[MI], b[4];
#pragma unroll
            for (int i = 0; i < MI; ++i)
                a[i] = *(const short8*)&As[(((wm * MI + i) * 2 + ks) * 64 + l) * 8];
#pragma unroll
            for (int ni = 0; ni < 4; ++ni)
                b[ni] = *(const short8*)&Bs[(((wn * 4 + ni) * 2 + ks) * 64 + l) * 8];
#pragma unroll
            for (int i = 0; i < MI; ++i)
#pragma unroll
                for (int ni = 0; ni < 4; ++ni)
                    acc[i][ni] = __builtin_amdgcn_mfma_f32_16x16x32_bf16(a[i], b[ni], acc[i][ni], 0, 0, 0);
        }
        __syncthreads();
    }
#pragma unroll
    for (int i = 0; i < MI; ++i) {
        int rbase = m0 + (wm * MI + i) * 16 + lg * 4;
#pragma unroll
        for (int ni = 0; ni < 4; ++ni) {
            int col = wn * 64 + ni * 16 + lr;
#pragma unroll
            for (int r = 0; r < 4; ++r) {
                int row = rbase + r;
                if (row < M) C[(long)row * N + col] = acc[i][ni][r] * dinv[row];
            }
        }
    }
}

// ---------------- small f32 GEMM with dinv epilogue (for layer 3: 128->32) ----------------
template <int KK, int NN>
__global__ __launch_bounds__(256) void gemm_small_kernel(const float* __restrict__ A,
                                                         const float* __restrict__ B,
                                                         const float* __restrict__ dinv,
                                                         float* __restrict__ C, int M) {
    __shared__ float Ws[KK * NN];
    __shared__ float Xs[64 * KK];
    int m0 = blockIdx.x * 64;
    for (int idx = threadIdx.x; idx < KK * NN; idx += 256) Ws[idx] = B[idx];
    for (int idx = threadIdx.x; idx < 64 * KK; idx += 256) {
        int r = idx / KK, c = idx % KK;
        int mm = m0 + r;
        Xs[idx] = (mm < M) ? A[(long)mm * KK + c] : 0.f;
    }
    __syncthreads();
    const int RG = 256 / NN;
    const int RPT = 64 / RG;
    int col = threadIdx.x % NN;
    int r0 = threadIdx.x / NN;
    float acc[RPT];
#pragma unroll
    for (int j = 0; j < RPT; j++) acc[j] = 0.f;
    for (int k = 0; k < KK; k++) {
        float w = Ws[k * NN + col];
#pragma unroll
        for (int j = 0; j < RPT; j++) acc[j] += Xs[(r0 + j * RG) * KK + k] * w;
    }
#pragma unroll
    for (int j = 0; j < RPT; j++) {
        int mm = m0 + r0 + j * RG;
        if (mm < M) C[(long)mm * NN + col] = acc[j] * dinv[mm];
    }
}

// ---------------- gather core: 8-deep unroll; base pre-offset by lane column ----------------
template <int R>   // row stride in f32x4 units
__device__ __forceinline__ f32x4 gather_sum2(const f32x4* __restrict__ base,
                                             const int* __restrict__ src,
                                             int beg, int end) {
    f32x4 acc = {0.f, 0.f, 0.f, 0.f};
    int e = beg;
    for (; e + 8 <= end; e += 8) {
        int s0 = src[e], s1 = src[e + 1], s2 = src[e + 2], s3 = src[e + 3];
        int s4 = src[e + 4], s5 = src[e + 5], s6 = src[e + 6], s7 = src[e + 7];
        f32x4 v0 = base[(long)s0 * R], v1 = base[(long)s1 * R];
        f32x4 v2 = base[(long)s2 * R], v3 = base[(long)s3 * R];
        f32x4 v4 = base[(long)s4 * R], v5 = base[(long)s5 * R];
        f32x4 v6 = base[(long)s6 * R], v7 = base[(long)s7 * R];
        acc += ((v0 + v1) + (v2 + v3)) + ((v4 + v5) + (v6 + v7));
    }
    for (; e + 2 <= end; e += 2) {
        int s0 = src[e], s1 = src[e + 1];
        acc += base[(long)s0 * R] + base[(long)s1 * R];
    }
    if (e < end) acc += base[(long)src[e] * R];
    return acc;
}

// ---------------- column-sliced aggregation (XCD-pinned heuristic) ----------------
// 8 slices x 16 floats (64B line per edge per slice); slice = blockIdx & 7 so each
// XCD's 4MB L2 holds one 3.2MB table slice (round-robin block->XCD assumption;
// perf-only bet, correctness unaffected). SPLIT: write bf16 [hi|lo] row (len 2D).
template <int D, bool SPLIT>
__global__ __launch_bounds__(256) void agg_sliced_kernel(const float* __restrict__ ts,
                                                         const int* __restrict__ row_ptr,
                                                         const int* __restrict__ src_sorted,
                                                         const float* __restrict__ dinv,
                                                         const float* __restrict__ bias,
                                                         float* __restrict__ out_f,
                                                         unsigned short* __restrict__ out_s,
                                                         int n, int colbase4) {
    int slice = blockIdx.x & 7;
    int chunk = blockIdx.x >> 3;
    int g = threadIdx.x >> 2;        // node within block (64 nodes/block)
    int lane = threadIdx.x & 3;
    int node = chunk * 64 + g;
    if (node >= n) return;
    int col4 = colbase4 + slice * 4 + lane;      // f32x4 column index
    const f32x4* base = (const f32x4*)ts + col4;
    f32x4 acc = gather_sum2<D / 4>(base, src_sorted, row_ptr[node], row_ptr[node + 1]);
    float di = dinv[node];
    f32x4 b4 = *(const f32x4*)&bias[col4 * 4];
    f32x4 v = acc * di + b4;
#pragma unroll
    for (int j = 0; j < 4; ++j) v[j] = fmaxf(v[j], 0.f);
    if constexpr (SPLIT) {
        u16x4 hi, lo;
#pragma unroll
        for (int j = 0; j < 4; ++j) {
            hi[j] = f2bf(v[j]);
            lo[j] = f2bf(v[j] - bf2f(hi[j]));
        }
        unsigned short* b = out_s + (long)node * 2 * D + col4 * 4;
        nt_store(hi, (u16x4*)b);
        nt_store(lo, (u16x4*)(b + D));
    } else {
        nt_store(v, (f32x4*)&out_f[(long)node * D + col4 * 4]);
    }
}

// D=32 agg + fused Wk matvec: tsk[node] = dinv * (relu(dinv*sum+b3) @ Wk)    (32 -> 8)
__global__ __launch_bounds__(256) void agg_fused_wk_kernel(const float* __restrict__ ts,
                                                           const int* __restrict__ row_ptr,
                                                           const int* __restrict__ src_sorted,
                                                           const float* __restrict__ dinv,
                                                           const float* __restrict__ bias,
                                                           const float* __restrict__ Wk,
                                                           float* __restrict__ tsk, int n) {
    __shared__ float Wks[32 * 8];
    __shared__ float hbuf[32][32];
    for (int i = threadIdx.x; i < 32 * 8; i += 256) Wks[i] = Wk[i];
    __syncthreads();
    int g = threadIdx.x >> 3, lane = threadIdx.x & 7;
    int node = blockIdx.x * 32 + g;
    if (node >= n) return;
    const f32x4* base = (const f32x4*)ts + lane;
    f32x4 acc = gather_sum2<8>(base, src_sorted, row_ptr[node], row_ptr[node + 1]);
    float di = dinv[node];
    f32x4 b4 = *(const f32x4*)&bias[lane * 4];
    f32x4 v = acc * di + b4;
#pragma unroll
    for (int j = 0; j < 4; ++j) v[j] = fmaxf(v[j], 0.f);
    *(f32x4*)&hbuf[g][lane * 4] = v;
    float aj = 0.f;
#pragma unroll
    for (int k = 0; k < 32; k += 4) {
        f32x4 hv = *(const f32x4*)&hbuf[g][k];
        aj += hv[0] * Wks[k * 8 + lane] + hv[1] * Wks[(k + 1) * 8 + lane]
            + hv[2] * Wks[(k + 2) * 8 + lane] + hv[3] * Wks[(k + 3) * 8 + lane];
    }
    tsk[(long)node * 8 + lane] = aj * di;
}

// D=8: z = relu(dinv*sum + bk)
__global__ __launch_bounds__(256) void agg_plain8_kernel(const float* __restrict__ ts,
                                                         const int* __restrict__ row_ptr,
                                                         const int* __restrict__ src_sorted,
                                                         const float* __restrict__ dinv,
                                                         const float* __restrict__ bias,
                                                         float* __restrict__ z, int n) {
    int g = threadIdx.x >> 1, lane = threadIdx.x & 1;
    int node = blockIdx.x * 128 + g;
    if (node >= n) return;
    const f32x4* base = (const f32x4*)ts + lane;
    f32x4 acc = gather_sum2<2>(base, src_sorted, row_ptr[node], row_ptr[node + 1]);
    float di = dinv[node];
    f32x4 b4 = *(const f32x4*)&bias[lane * 4];
    f32x4 v = acc * di + b4;
#pragma unroll
    for (int j = 0; j < 4; ++j) v[j] = fmaxf(v[j], 0.f);
    *(f32x4*)&z[(long)node * 8 + lane * 4] = v;
}

// ---------------- decoder: out[k,e] = dot(z[s_e], z[d_e]) (identical across k) ----------------
__global__ __launch_bounds__(256) void decoder_kernel(const float* __restrict__ z,
                                                      const int* __restrict__ ei,
                                                      float* __restrict__ out,
                                                      int E, int K) {
    int e = blockIdx.x * blockDim.x + threadIdx.x;
    if (e >= E) return;
    int s = ei[e];
    int d = ei[E + e];
    const f32x4* zv = (const f32x4*)z;
    f32x4 a0 = zv[(long)s * 2], a1 = zv[(long)s * 2 + 1];
    f32x4 b0 = zv[(long)d * 2], b1 = zv[(long)d * 2 + 1];
    f32x4 p = a0 * b0 + a1 * b1;
    float acc = p[0] + p[1] + p[2] + p[3];
    for (int k = 0; k < K; k++) nt_store(acc, &out[(long)k * E + e]);
}

// ---------------- launch ----------------

extern "C" void kernel_launch(void* const* d_in, const int* in_sizes, int n_in,
                              void* d_out, int out_size, void* d_ws, size_t ws_size,
                              hipStream_t stream) {
    const float* x  = (const float*)d_in[0];
    const int*   ei = (const int*)d_in[1];
    const float* W1 = (const float*)d_in[3];
    const float* b1 = (const float*)d_in[4];
    const float* W2 = (const float*)d_in[5];
    const float* b2 = (const float*)d_in[6];
    const float* W3 = (const float*)d_in[7];
    const float* b3 = (const float*)d_in[8];
    const float* Wk = (const float*)d_in[9];
    const float* bk = (const float*)d_in[10];
    float* out = (float*)d_out;

    const int D1 = in_sizes[4];            // 256
    const int D2 = in_sizes[6];            // 128
    const int F  = in_sizes[3] / D1;       // 256
    const int N  = in_sizes[0] / F;        // 50000
    const int E  = in_sizes[1] / 2;        // 800000
    const int K  = out_size / E;           // 8
    const int M  = E + N;                  // edges incl self loops
    const int Mpad = (N + 127) & ~127;     // 50048

    size_t off = 0;
    auto alloc = [&](size_t bytes) -> void* {
        off = (off + 255) & ~(size_t)255;
        void* p = (char*)d_ws + off;
        off += bytes;
        return p;
    };
    int*   cnt        = (int*)alloc((size_t)N * sizeof(int));
    int*   row_ptr    = (int*)alloc((size_t)(N + 1) * sizeof(int));
    int*   cursor     = (int*)alloc((size_t)N * sizeof(int));
    float* dinv       = (float*)alloc((size_t)N * sizeof(float));
    int*   src_sorted = (int*)alloc((size_t)M * sizeof(int));
    unsigned short* region_x = (unsigned short*)alloc((size_t)Mpad * 2 * F * sizeof(short));  // xs -> h1s (51.2MB)
    float* region_t   = (float*)alloc((size_t)Mpad * 256 * sizeof(float));                    // ts1 -> ts2|h2 (51.2MB)
    unsigned short* Wt1 = (unsigned short*)alloc((size_t)D1 * 3 * F * sizeof(short));
    unsigned short* Wt2 = (unsigned short*)alloc((size_t)D2 * 3 * D1 * sizeof(short));
    float* ts3        = (float*)alloc((size_t)Mpad * 32 * sizeof(float));
    float* tsk        = (float*)alloc((size_t)Mpad * 8 * sizeof(float));
    float* z          = (float*)alloc((size_t)Mpad * 8 * sizeof(float));
    (void)ws_size; (void)n_in;

    unsigned short* xs  = region_x;
    unsigned short* h1s = region_x;           // reused after GEMM1 consumed xs
    float* ts1 = region_t;                    // [Mpad,256]
    float* ts2 = region_t;                    // [Mpad,128] (overwrites ts1; h1s already consumed it)
    float* h2  = region_t + (size_t)Mpad * 128;  // [Mpad,128]

    int nbN = (N + THREADS - 1) / THREADS;
    int nbE = (E + THREADS - 1) / THREADS;
    int nbS = 8 * ((N + 63) / 64);            // sliced-agg grid

    // ---- graph prep ----
    init_cnt_kernel<<<nbN, THREADS, 0, stream>>>(cnt, N);
    count_edges_kernel<<<nbE, THREADS, 0, stream>>>(ei, cnt, E);
    scan_kernel<<<1, 1024, 0, stream>>>(cnt, row_ptr, N);
    prep_fused_kernel<<<nbN, THREADS, 0, stream>>>(cnt, row_ptr, cursor, dinv, src_sorted, N);
    fill_edges_kernel<<<nbE, THREADS, 0, stream>>>(ei, cursor, src_sorted, E);

    // ---- conversions ----
    convert_x_kernel<<<(int)(((long)N * (F / 4) + 255) / 256), THREADS, 0, stream>>>(x, xs, N, F);
    convert_w_kernel<<<(F * D1 + 255) / 256, THREADS, 0, stream>>>(W1, Wt1, F, D1);
    convert_w_kernel<<<(D1 * D2 + 255) / 256, THREADS, 0, stream>>>(W2, Wt2, D1, D2);

    // ---- layer 1: ts1 = dinv .* (x @ W1)  [MFMA]; sliced agg (2 half-column launches) ----
    gemm_bf16_kernel<256><<<Mpad / 64, THREADS, 0, stream>>>(xs, Wt1, dinv, ts1, N, 2 * F, 3 * F, D1);
    agg_sliced_kernel<256, true><<<nbS, THREADS, 0, stream>>>(ts1, row_ptr, src_sorted, dinv, b1, nullptr, h1s, N, 0);
    agg_sliced_kernel<256, true><<<nbS, THREADS, 0, stream>>>(ts1, row_ptr, src_sorted, dinv, b1, nullptr, h1s, N, 32);

    // ---- layer 2: ts2 = dinv .* (h1 @ W2)  [MFMA]; sliced agg (1 launch) ----
    gemm_bf16_kernel<128><<<Mpad / 64, THREADS, 0, stream>>>(h1s, Wt2, dinv, ts2, N, 2 * D1, 3 * D1, D2);
    agg_sliced_kernel<128, false><<<nbS, THREADS, 0, stream>>>(ts2, row_ptr, src_sorted, dinv, b2, h2, nullptr, N, 0);

    // ---- layer 3: ts3 = dinv .* (h2 @ W3)  (128 -> 32) ----
    gemm_small_kernel<128, 32><<<(N + 63) / 64, THREADS, 0, stream>>>(h2, W3, dinv, ts3, N);

    // ---- layer 3 agg + fused Wk (32 -> 8), then final agg ----
    agg_fused_wk_kernel<<<(N + 31) / 32, THREADS, 0, stream>>>(ts3, row_ptr, src_sorted, dinv, b3, Wk, tsk, N);
    agg_plain8_kernel<<<(N + 127) / 128, THREADS, 0, stream>>>(tsk, row_ptr, src_sorted, dinv, bk, z, N);

    // ---- decoder ----
    decoder_kernel<<<nbE, THREADS, 0, stream>>>(z, ei, out, E, K);
}

// Round 8
// 461.370 us; speedup vs baseline: 1.3644x; 1.3644x over previous
//
#include <hip/hip_runtime.h>
#include <hip/hip_bf16.h>

#define THREADS 256

typedef __attribute__((ext_vector_type(2))) float f32x2;
typedef __attribute__((ext_vector_type(4))) float f32x4;
typedef __attribute__((ext_vector_type(8))) float f32x8;
typedef __attribute__((ext_vector_type(8))) short short8;
typedef __attribute__((ext_vector_type(4))) unsigned short u16x4;
typedef __attribute__((ext_vector_type(8))) unsigned short u16x8;

__device__ inline unsigned short f2bf(float f) {
    unsigned int u = __builtin_bit_cast(unsigned int, f);
    unsigned int r = (u + 0x7FFFu + ((u >> 16) & 1u)) >> 16;
    return (unsigned short)r;
}
__device__ inline float bf2f(unsigned short h) {
    unsigned int u = ((unsigned int)h) << 16;
    return __builtin_bit_cast(float, u);
}
__device__ __forceinline__ f32x8 bfv8(u16x8 v) {
    f32x8 r;
#pragma unroll
    for (int j = 0; j < 8; ++j) r[j] = bf2f(v[j]);
    return r;
}

#if defined(__has_builtin)
#if __has_builtin(__builtin_amdgcn_global_load_lds)
#define HAVE_GLOAD_LDS 1
#endif
#endif

// One 16B chunk per lane; lds base must be wave-uniform (HW: base + lane*16).
__device__ __forceinline__ void async_copy16(const void* g, void* lds) {
#ifdef HAVE_GLOAD_LDS
    __builtin_amdgcn_global_load_lds((const __attribute__((address_space(1))) void*)g,
                                     (__attribute__((address_space(3))) void*)lds, 16, 0, 0);
#else
    int lane = threadIdx.x & 63;
    *(short8*)((short*)lds + lane * 8) = *(const short8*)g;
#endif
}

// ---------------- graph preprocessing ----------------

__global__ __launch_bounds__(256) void init_cnt_kernel(int* cnt, int n) {
    int i = blockIdx.x * blockDim.x + threadIdx.x;
    if (i < n) cnt[i] = 1;   // self loop
}

__global__ __launch_bounds__(256) void count_edges_kernel(const int* ei, int* cnt, int E) {
    int e = blockIdx.x * blockDim.x + threadIdx.x;
    if (e < E) atomicAdd(&cnt[ei[E + e]], 1);   // dst row
}

// single-block exclusive scan: 1024 threads, chunked
__global__ __launch_bounds__(1024) void scan_kernel(const int* cnt, int* row_ptr, int n) {
    __shared__ int sh[1024];
    int chunk = (n + 1023) >> 10;
    int beg = (int)threadIdx.x * chunk;
    int end = min(beg + chunk, n);
    int s = 0;
    for (int i = beg; i < end; ++i) s += cnt[i];
    sh[threadIdx.x] = s;
    __syncthreads();
    for (int off = 1; off < 1024; off <<= 1) {
        int t = (threadIdx.x >= (unsigned)off) ? sh[threadIdx.x - off] : 0;
        __syncthreads();
        sh[threadIdx.x] += t;
        __syncthreads();
    }
    int run = sh[threadIdx.x] - s;   // exclusive prefix
    for (int i = beg; i < end; ++i) { row_ptr[i] = run; run += cnt[i]; }
    if (threadIdx.x == 1023) row_ptr[n] = run;
}

// dinv + self-fill + cursor init in one pass
__global__ __launch_bounds__(256) void prep_fused_kernel(const int* cnt, const int* row_ptr,
                                                         int* cursor, float* dinv,
                                                         int* src_sorted, int n) {
    int i = blockIdx.x * blockDim.x + threadIdx.x;
    if (i < n) {
        dinv[i] = rsqrtf((float)cnt[i]);
        int p = row_ptr[i];
        src_sorted[p] = i;     // self loop first (deterministic slot)
        cursor[i] = p + 1;
    }
}

__global__ __launch_bounds__(256) void fill_edges_kernel(const int* ei, int* cursor, int* src_sorted, int E) {
    int e = blockIdx.x * blockDim.x + threadIdx.x;
    if (e < E) {
        int s = ei[e];
        int d = ei[E + e];
        int pos = atomicAdd(&cursor[d], 1);
        src_sorted[pos] = s;
    }
}

// ---------------- split-bf16 conversion ----------------
// x -> [hi | lo]  (row length 2F)
__global__ __launch_bounds__(256) void convert_x_kernel(const float* __restrict__ x,
                                                        unsigned short* __restrict__ xs,
                                                        int n, int F) {
    long idx = (long)blockIdx.x * 256 + threadIdx.x;
    long total = (long)n * (F / 4);
    if (idx >= total) return;
    int row = (int)(idx / (F / 4));
    int c4 = (int)(idx % (F / 4)) * 4;
    f32x4 v = *(const f32x4*)&x[(long)row * F + c4];
    u16x4 hi, lo;
#pragma unroll
    for (int j = 0; j < 4; ++j) {
        hi[j] = f2bf(v[j]);
        lo[j] = f2bf(v[j] - bf2f(hi[j]));
    }
    unsigned short* base = xs + (long)row * 2 * F;
    *(u16x4*)&base[c4] = hi;
    *(u16x4*)&base[F + c4] = lo;
}

// W [K,N] f32 -> Wt [N, 3K] bf16 transposed: rows of B' = [hi; hi; lo]
__global__ __launch_bounds__(256) void convert_w_kernel(const float* __restrict__ W,
                                                        unsigned short* __restrict__ Wt,
                                                        int K, int N) {
    int idx = blockIdx.x * 256 + threadIdx.x;
    if (idx >= K * N) return;
    int k = idx / N, n = idx % N;
    float v = W[(long)k * N + n];
    unsigned short hi = f2bf(v);
    unsigned short lo = f2bf(v - bf2f(hi));
    unsigned short* base = Wt + (long)n * 3 * K;
    base[k] = hi;
    base[K + k] = hi;
    base[2 * K + k] = lo;
}

// ---------------- MFMA bf16 GEMM: C[M,N] = A'[M,Kp] * Bt[N,Kp]^T, epilogue *dinv[row], C in bf16 ----------------
// BM=64, BN=N (one column block, A read exactly once), BK=64, 256 threads = 4 waves.
// A stored [hi|lo] (row len KA=2F); logical third segment [2F,3F) remapped to hi.
// LDS fragment-chunk layout -> conflict-free b128, global_load_lds 16B staging.
template <int BN>
__global__ __launch_bounds__(256) void gemm_bf16_kernel(const unsigned short* __restrict__ A,
                                                        const unsigned short* __restrict__ Bt,
                                                        const float* __restrict__ dinv,
                                                        unsigned short* __restrict__ C,
                                                        int M, int KA, int Kp, int N) {
    constexpr int WAVES_N = BN / 64;
    constexpr int WAVES_M = 4 / WAVES_N;
    constexpr int MI = 4 / WAVES_M;       // 16-row tiles per wave (BM=64)
    constexpr int AITERS = 2;             // 512 A-chunks / 256 threads
    constexpr int BITERS = BN / 32;       // (BN/16)*2*64 / 256
    __shared__ short As[64 * 64];
    __shared__ short Bs[BN * 64];
    const int tid = threadIdx.x;
    const int m0 = blockIdx.x * 64;
    const int wave = tid >> 6, l = tid & 63;
    const int wn = wave / WAVES_M, wm = wave % WAVES_M;
    const int lr = l & 15, lg = l >> 4;
    f32x4 acc[MI][4] = {};
    for (int k0 = 0; k0 < Kp; k0 += 64) {
#pragma unroll
        for (int it = 0; it < AITERS; ++it) {
            int chunk = it * 256 + tid;
            int mi = chunk >> 7, ks = (chunk >> 6) & 1, cl = chunk & 63;
            long row = m0 + mi * 16 + (cl & 15);
            int gk = k0 + ks * 32 + ((cl >> 4) << 3);
            if (gk >= KA) gk -= KA;       // [hi|lo|hi] logical from [hi|lo] storage
            async_copy16(&A[row * KA + gk], &As[(size_t)(it * 256 + (tid & ~63)) * 8]);
        }
#pragma unroll
        for (int it = 0; it < BITERS; ++it) {
            int chunk = it * 256 + tid;
            int ni = chunk >> 7, ks = (chunk >> 6) & 1, cl = chunk & 63;
            long col = ni * 16 + (cl & 15);
            int gk = k0 + ks * 32 + ((cl >> 4) << 3);
            async_copy16(&Bt[col * Kp + gk], &Bs[(size_t)(it * 256 + (tid & ~63)) * 8]);
        }
        __syncthreads();
#pragma unroll
        for (int ks = 0; ks < 2; ++ks) {
            short8 a[MI], b[4];
#pragma unroll
            for (int i = 0; i < MI; ++i)
                a[i] = *(const short8*)&As[(((wm * MI + i) * 2 + ks) * 64 + l) * 8];
#pragma unroll
            for (int ni = 0; ni < 4; ++ni)
                b[ni] = *(const short8*)&Bs[(((wn * 4 + ni) * 2 + ks) * 64 + l) * 8];
#pragma unroll
            for (int i = 0; i < MI; ++i)
#pragma unroll
                for (int ni = 0; ni < 4; ++ni)
                    acc[i][ni] = __builtin_amdgcn_mfma_f32_16x16x32_bf16(a[i], b[ni], acc[i][ni], 0, 0, 0);
        }
        __syncthreads();
    }
#pragma unroll
    for (int i = 0; i < MI; ++i) {
        int rbase = m0 + (wm * MI + i) * 16 + lg * 4;
#pragma unroll
        for (int ni = 0; ni < 4; ++ni) {
            int col = wn * 64 + ni * 16 + lr;
#pragma unroll
            for (int r = 0; r < 4; ++r) {
                int row = rbase + r;
                if (row < M) C[(long)row * N + col] = f2bf(acc[i][ni][r] * dinv[row]);
            }
        }
    }
}

// ---------------- bf16 gather core: 8-deep unroll, u16x8 (16B) per lane ----------------
template <int R8>   // row stride in u16x8 units
__device__ __forceinline__ f32x8 gather_sum_bf(const u16x8* __restrict__ base,
                                               const int* __restrict__ src,
                                               int beg, int end) {
    f32x8 acc = {0.f, 0.f, 0.f, 0.f, 0.f, 0.f, 0.f, 0.f};
    int e = beg;
    for (; e + 8 <= end; e += 8) {
        u16x8 v0 = base[(long)src[e] * R8],     v1 = base[(long)src[e + 1] * R8];
        u16x8 v2 = base[(long)src[e + 2] * R8], v3 = base[(long)src[e + 3] * R8];
        u16x8 v4 = base[(long)src[e + 4] * R8], v5 = base[(long)src[e + 5] * R8];
        u16x8 v6 = base[(long)src[e + 6] * R8], v7 = base[(long)src[e + 7] * R8];
        acc += ((bfv8(v0) + bfv8(v1)) + (bfv8(v2) + bfv8(v3)))
             + ((bfv8(v4) + bfv8(v5)) + (bfv8(v6) + bfv8(v7)));
    }
    for (; e < end; ++e) acc += bfv8(base[(long)src[e] * R8]);
    return acc;
}

// ---------------- f32 gather core (layers 3/4) ----------------
template <int G>
__device__ __forceinline__ f32x4 gather_sum(const f32x4* __restrict__ tsv,
                                            const int* __restrict__ src,
                                            int beg, int end, int lane) {
    f32x4 acc = {0.f, 0.f, 0.f, 0.f};
    int e = beg;
    for (; e + 8 <= end; e += 8) {
        int s0 = src[e], s1 = src[e + 1], s2 = src[e + 2], s3 = src[e + 3];
        int s4 = src[e + 4], s5 = src[e + 5], s6 = src[e + 6], s7 = src[e + 7];
        f32x4 v0 = tsv[(long)s0 * G + lane], v1 = tsv[(long)s1 * G + lane];
        f32x4 v2 = tsv[(long)s2 * G + lane], v3 = tsv[(long)s3 * G + lane];
        f32x4 v4 = tsv[(long)s4 * G + lane], v5 = tsv[(long)s5 * G + lane];
        f32x4 v6 = tsv[(long)s6 * G + lane], v7 = tsv[(long)s7 * G + lane];
        acc += ((v0 + v1) + (v2 + v3)) + ((v4 + v5) + (v6 + v7));
    }
    for (; e + 2 <= end; e += 2) {
        int s0 = src[e], s1 = src[e + 1];
        acc += tsv[(long)s0 * G + lane] + tsv[(long)s1 * G + lane];
    }
    if (e < end) acc += tsv[(long)src[e] * G + lane];
    return acc;
}

// D=256 bf16 gather: h1 = relu(dinv*sum + b1) -> split bf16 [hi|lo] write (row len 512)
__global__ __launch_bounds__(256) void agg_split256_kernel(const unsigned short* __restrict__ ts,
                                                           const int* __restrict__ row_ptr,
                                                           const int* __restrict__ src_sorted,
                                                           const float* __restrict__ dinv,
                                                           const float* __restrict__ bias,
                                                           unsigned short* __restrict__ out_s,
                                                           int n) {
    int g = threadIdx.x >> 5, lane = threadIdx.x & 31;   // 8 nodes/block, 32 lanes/node
    int node = blockIdx.x * 8 + g;
    if (node >= n) return;
    const u16x8* base = (const u16x8*)ts + lane;         // row stride 32 chunks
    f32x8 acc = gather_sum_bf<32>(base, src_sorted, row_ptr[node], row_ptr[node + 1]);
    float di = dinv[node];
    f32x8 b8 = *(const f32x8*)&bias[lane * 8];
    f32x8 v = acc * di + b8;
    u16x8 hi, lo;
#pragma unroll
    for (int j = 0; j < 8; ++j) {
        float r = fmaxf(v[j], 0.f);
        hi[j] = f2bf(r);
        lo[j] = f2bf(r - bf2f(hi[j]));
    }
    unsigned short* ob = out_s + (long)node * 512 + lane * 8;
    *(u16x8*)ob = hi;
    *(u16x8*)(ob + 256) = lo;
}

// D=128 bf16 gather + fused W3 matvec: ts3[node] = dinv * (relu(dinv*sum+b2) @ W3)  (128 -> 32)
__global__ __launch_bounds__(256) void agg_fused_w3_kernel(const unsigned short* __restrict__ ts,
                                                           const int* __restrict__ row_ptr,
                                                           const int* __restrict__ src_sorted,
                                                           const float* __restrict__ dinv,
                                                           const float* __restrict__ bias,
                                                           const float* __restrict__ W3,
                                                           float* __restrict__ ts3, int n) {
    __shared__ float W3s[128 * 32];
    __shared__ float hbuf[16][132];   // +4 pad: spreads per-node broadcast reads across banks
    for (int i = threadIdx.x; i < 128 * 32; i += 256) W3s[i] = W3[i];
    __syncthreads();
    int g = threadIdx.x >> 4, lane = threadIdx.x & 15;   // 16 nodes/block, 16 lanes/node
    int node = blockIdx.x * 16 + g;
    if (node >= n) return;
    const u16x8* base = (const u16x8*)ts + lane;         // row stride 16 chunks
    f32x8 acc = gather_sum_bf<16>(base, src_sorted, row_ptr[node], row_ptr[node + 1]);
    float di = dinv[node];
    f32x8 b8 = *(const f32x8*)&bias[lane * 8];
    f32x8 v = acc * di + b8;
#pragma unroll
    for (int j = 0; j < 8; ++j) v[j] = fmaxf(v[j], 0.f);
    f32x4 vlo = {v[0], v[1], v[2], v[3]};
    f32x4 vhi = {v[4], v[5], v[6], v[7]};
    *(f32x4*)&hbuf[g][lane * 8] = vlo;        // same-wave DS: in-order, no barrier needed
    *(f32x4*)&hbuf[g][lane * 8 + 4] = vhi;
    int c0 = lane * 2;
    float aj0 = 0.f, aj1 = 0.f;
#pragma unroll
    for (int k = 0; k < 128; k += 4) {
        f32x4 hv = *(const f32x4*)&hbuf[g][k];
        aj0 += hv[0] * W3s[k * 32 + c0] + hv[1] * W3s[(k + 1) * 32 + c0]
             + hv[2] * W3s[(k + 2) * 32 + c0] + hv[3] * W3s[(k + 3) * 32 + c0];
        aj1 += hv[0] * W3s[k * 32 + c0 + 1] + hv[1] * W3s[(k + 1) * 32 + c0 + 1]
             + hv[2] * W3s[(k + 2) * 32 + c0 + 1] + hv[3] * W3s[(k + 3) * 32 + c0 + 1];
    }
    f32x2 o = {aj0 * di, aj1 * di};
    *(f32x2*)&ts3[(long)node * 32 + c0] = o;
}

// D=32 agg + fused Wk matvec: tsk[node] = dinv * (relu(dinv*sum+b3) @ Wk)    (32 -> 8)
__global__ __launch_bounds__(256) void agg_fused_wk_kernel(const float* __restrict__ ts,
                                                           const int* __restrict__ row_ptr,
                                                           const int* __restrict__ src_sorted,
                                                           const float* __restrict__ dinv,
                                                           const float* __restrict__ bias,
                                                           const float* __restrict__ Wk,
                                                           float* __restrict__ tsk, int n) {
    __shared__ float Wks[32 * 8];
    __shared__ float hbuf[32][36];   // +4 pad
    for (int i = threadIdx.x; i < 32 * 8; i += 256) Wks[i] = Wk[i];
    __syncthreads();
    int g = threadIdx.x >> 3, lane = threadIdx.x & 7;
    int node = blockIdx.x * 32 + g;
    if (node >= n) return;
    f32x4 acc = gather_sum<8>((const f32x4*)ts, src_sorted, row_ptr[node], row_ptr[node + 1], lane);
    float di = dinv[node];
    f32x4 b4 = *(const f32x4*)&bias[lane * 4];
    f32x4 v = acc * di + b4;
#pragma unroll
    for (int j = 0; j < 4; ++j) v[j] = fmaxf(v[j], 0.f);
    *(f32x4*)&hbuf[g][lane * 4] = v;
    float aj = 0.f;
#pragma unroll
    for (int k = 0; k < 32; k += 4) {
        f32x4 hv = *(const f32x4*)&hbuf[g][k];
        aj += hv[0] * Wks[k * 8 + lane] + hv[1] * Wks[(k + 1) * 8 + lane]
            + hv[2] * Wks[(k + 2) * 8 + lane] + hv[3] * Wks[(k + 3) * 8 + lane];
    }
    tsk[(long)node * 8 + lane] = aj * di;
}

// D=8: z = relu(dinv*sum + bk)
__global__ __launch_bounds__(256) void agg_plain8_kernel(const float* __restrict__ ts,
                                                         const int* __restrict__ row_ptr,
                                                         const int* __restrict__ src_sorted,
                                                         const float* __restrict__ dinv,
                                                         const float* __restrict__ bias,
                                                         float* __restrict__ z, int n) {
    int g = threadIdx.x >> 1, lane = threadIdx.x & 1;
    int node = blockIdx.x * 128 + g;
    if (node >= n) return;
    f32x4 acc = gather_sum<2>((const f32x4*)ts, src_sorted, row_ptr[node], row_ptr[node + 1], lane);
    float di = dinv[node];
    f32x4 b4 = *(const f32x4*)&bias[lane * 4];
    f32x4 v = acc * di + b4;
#pragma unroll
    for (int j = 0; j < 4; ++j) v[j] = fmaxf(v[j], 0.f);
    *(f32x4*)&z[(long)node * 8 + lane * 4] = v;
}

// ---------------- decoder: out[k,e] = dot(z[s_e], z[d_e]) (identical across k) ----------------
__global__ __launch_bounds__(256) void decoder_kernel(const float* __restrict__ z,
                                                      const int* __restrict__ ei,
                                                      float* __restrict__ out,
                                                      int E, int K) {
    int e = blockIdx.x * blockDim.x + threadIdx.x;
    if (e >= E) return;
    int s = ei[e];
    int d = ei[E + e];
    const f32x4* zv = (const f32x4*)z;
    f32x4 a0 = zv[(long)s * 2], a1 = zv[(long)s * 2 + 1];
    f32x4 b0 = zv[(long)d * 2], b1 = zv[(long)d * 2 + 1];
    f32x4 p = a0 * b0 + a1 * b1;
    float acc = p[0] + p[1] + p[2] + p[3];
    for (int k = 0; k < K; k++) out[(long)k * E + e] = acc;
}

// ---------------- launch ----------------

extern "C" void kernel_launch(void* const* d_in, const int* in_sizes, int n_in,
                              void* d_out, int out_size, void* d_ws, size_t ws_size,
                              hipStream_t stream) {
    const float* x  = (const float*)d_in[0];
    const int*   ei = (const int*)d_in[1];
    const float* W1 = (const float*)d_in[3];
    const float* b1 = (const float*)d_in[4];
    const float* W2 = (const float*)d_in[5];
    const float* b2 = (const float*)d_in[6];
    const float* W3 = (const float*)d_in[7];
    const float* b3 = (const float*)d_in[8];
    const float* Wk = (const float*)d_in[9];
    const float* bk = (const float*)d_in[10];
    float* out = (float*)d_out;

    const int D1 = in_sizes[4];            // 256
    const int D2 = in_sizes[6];            // 128
    const int F  = in_sizes[3] / D1;       // 256
    const int N  = in_sizes[0] / F;        // 50000
    const int E  = in_sizes[1] / 2;        // 800000
    const int K  = out_size / E;           // 8
    const int M  = E + N;                  // edges incl self loops
    const int Mpad = (N + 127) & ~127;     // 50048

    size_t off = 0;
    auto alloc = [&](size_t bytes) -> void* {
        off = (off + 255) & ~(size_t)255;
        void* p = (char*)d_ws + off;
        off += bytes;
        return p;
    };
    int*   cnt        = (int*)alloc((size_t)N * sizeof(int));
    int*   row_ptr    = (int*)alloc((size_t)(N + 1) * sizeof(int));
    int*   cursor     = (int*)alloc((size_t)N * sizeof(int));
    float* dinv       = (float*)alloc((size_t)N * sizeof(float));
    int*   src_sorted = (int*)alloc((size_t)M * sizeof(int));
    unsigned short* region_x = (unsigned short*)alloc((size_t)Mpad * 2 * F * sizeof(short));  // xs -> h1s (51.2MB)
    float* region_t   = (float*)alloc((size_t)Mpad * 256 * sizeof(float));                    // ts1/ts2 (as bf16)
    unsigned short* Wt1 = (unsigned short*)alloc((size_t)D1 * 3 * F * sizeof(short));
    unsigned short* Wt2 = (unsigned short*)alloc((size_t)D2 * 3 * D1 * sizeof(short));
    float* ts3        = (float*)alloc((size_t)Mpad * 32 * sizeof(float));
    float* tsk        = (float*)alloc((size_t)Mpad * 8 * sizeof(float));
    float* z          = (float*)alloc((size_t)Mpad * 8 * sizeof(float));
    (void)ws_size; (void)n_in;

    unsigned short* xs  = region_x;
    unsigned short* h1s = region_x;                 // reused after GEMM1 consumed xs
    unsigned short* ts1 = (unsigned short*)region_t;  // [Mpad,256] bf16 (25.6MB)
    unsigned short* ts2 = (unsigned short*)region_t;  // [Mpad,128] bf16 (ts1 consumed)

    int nbN = (N + THREADS - 1) / THREADS;
    int nbE = (E + THREADS - 1) / THREADS;

    // ---- graph prep ----
    init_cnt_kernel<<<nbN, THREADS, 0, stream>>>(cnt, N);
    count_edges_kernel<<<nbE, THREADS, 0, stream>>>(ei, cnt, E);
    scan_kernel<<<1, 1024, 0, stream>>>(cnt, row_ptr, N);
    prep_fused_kernel<<<nbN, THREADS, 0, stream>>>(cnt, row_ptr, cursor, dinv, src_sorted, N);
    fill_edges_kernel<<<nbE, THREADS, 0, stream>>>(ei, cursor, src_sorted, E);

    // ---- conversions ----
    convert_x_kernel<<<(int)(((long)N * (F / 4) + 255) / 256), THREADS, 0, stream>>>(x, xs, N, F);
    convert_w_kernel<<<(F * D1 + 255) / 256, THREADS, 0, stream>>>(W1, Wt1, F, D1);
    convert_w_kernel<<<(D1 * D2 + 255) / 256, THREADS, 0, stream>>>(W2, Wt2, D1, D2);

    // ---- layer 1: ts1 = bf16(dinv .* (x @ W1)); agg (bf16 gather) -> h1s [hi|lo] ----
    gemm_bf16_kernel<256><<<Mpad / 64, THREADS, 0, stream>>>(xs, Wt1, dinv, ts1, N, 2 * F, 3 * F, D1);
    agg_split256_kernel<<<(N + 7) / 8, THREADS, 0, stream>>>(ts1, row_ptr, src_sorted, dinv, b1, h1s, N);

    // ---- layer 2: ts2 = bf16(dinv .* (h1 @ W2)); agg (bf16 gather) + fused W3 -> ts3 ----
    gemm_bf16_kernel<128><<<Mpad / 64, THREADS, 0, stream>>>(h1s, Wt2, dinv, ts2, N, 2 * D1, 3 * D1, D2);
    agg_fused_w3_kernel<<<(N + 15) / 16, THREADS, 0, stream>>>(ts2, row_ptr, src_sorted, dinv, b2, W3, ts3, N);

    // ---- layer 3 agg + fused Wk (32 -> 8), then final agg ----
    agg_fused_wk_kernel<<<(N + 31) / 32, THREADS, 0, stream>>>(ts3, row_ptr, src_sorted, dinv, b3, Wk, tsk, N);
    agg_plain8_kernel<<<(N + 127) / 128, THREADS, 0, stream>>>(tsk, row_ptr, src_sorted, dinv, bk, z, N);

    // ---- decoder ----
    decoder_kernel<<<nbE, THREADS, 0, stream>>>(z, ei, out, E, K);
}

// Round 9
// 453.718 us; speedup vs baseline: 1.3874x; 1.0169x over previous
//
#include <hip/hip_runtime.h>
#include <hip/hip_bf16.h>

#define THREADS 256

typedef __attribute__((ext_vector_type(2))) float f32x2;
typedef __attribute__((ext_vector_type(4))) float f32x4;
typedef __attribute__((ext_vector_type(8))) float f32x8;
typedef __attribute__((ext_vector_type(8))) short short8;
typedef __attribute__((ext_vector_type(4))) unsigned short u16x4;
typedef __attribute__((ext_vector_type(8))) unsigned short u16x8;

__device__ inline unsigned short f2bf(float f) {
    unsigned int u = __builtin_bit_cast(unsigned int, f);
    unsigned int r = (u + 0x7FFFu + ((u >> 16) & 1u)) >> 16;
    return (unsigned short)r;
}
__device__ inline float bf2f(unsigned short h) {
    unsigned int u = ((unsigned int)h) << 16;
    return __builtin_bit_cast(float, u);
}
__device__ __forceinline__ f32x8 bfv8(u16x8 v) {
    f32x8 r;
#pragma unroll
    for (int j = 0; j < 8; ++j) r[j] = bf2f(v[j]);
    return r;
}

#if defined(__has_builtin)
#if __has_builtin(__builtin_amdgcn_global_load_lds)
#define HAVE_GLOAD_LDS 1
#endif
#endif

// One 16B chunk per lane; lds base must be wave-uniform (HW: base + lane*16).
__device__ __forceinline__ void async_copy16(const void* g, void* lds) {
#ifdef HAVE_GLOAD_LDS
    __builtin_amdgcn_global_load_lds((const __attribute__((address_space(1))) void*)g,
                                     (__attribute__((address_space(3))) void*)lds, 16, 0, 0);
#else
    int lane = threadIdx.x & 63;
    *(short8*)((short*)lds + lane * 8) = *(const short8*)g;
#endif
}

// ---------------- graph preprocessing ----------------

__global__ __launch_bounds__(256) void init_cnt_kernel(int* cnt, int n) {
    int i = blockIdx.x * blockDim.x + threadIdx.x;
    if (i < n) cnt[i] = 1;   // self loop
}

__global__ __launch_bounds__(256) void count_edges_kernel(const int* ei, int* cnt, int E) {
    int e = blockIdx.x * blockDim.x + threadIdx.x;
    if (e < E) atomicAdd(&cnt[ei[E + e]], 1);   // dst row
}

// single-block exclusive scan: 1024 threads, chunked
__global__ __launch_bounds__(1024) void scan_kernel(const int* cnt, int* row_ptr, int n) {
    __shared__ int sh[1024];
    int chunk = (n + 1023) >> 10;
    int beg = (int)threadIdx.x * chunk;
    int end = min(beg + chunk, n);
    int s = 0;
    for (int i = beg; i < end; ++i) s += cnt[i];
    sh[threadIdx.x] = s;
    __syncthreads();
    for (int off = 1; off < 1024; off <<= 1) {
        int t = (threadIdx.x >= (unsigned)off) ? sh[threadIdx.x - off] : 0;
        __syncthreads();
        sh[threadIdx.x] += t;
        __syncthreads();
    }
    int run = sh[threadIdx.x] - s;   // exclusive prefix
    for (int i = beg; i < end; ++i) { row_ptr[i] = run; run += cnt[i]; }
    if (threadIdx.x == 1023) row_ptr[n] = run;
}

// dinv + self-fill + cursor init in one pass
__global__ __launch_bounds__(256) void prep_fused_kernel(const int* cnt, const int* row_ptr,
                                                         int* cursor, float* dinv,
                                                         int* src_sorted, int n) {
    int i = blockIdx.x * blockDim.x + threadIdx.x;
    if (i < n) {
        dinv[i] = rsqrtf((float)cnt[i]);
        int p = row_ptr[i];
        src_sorted[p] = i;     // self loop first (deterministic slot)
        cursor[i] = p + 1;
    }
}

__global__ __launch_bounds__(256) void fill_edges_kernel(const int* ei, int* cursor, int* src_sorted, int E) {
    int e = blockIdx.x * blockDim.x + threadIdx.x;
    if (e < E) {
        int s = ei[e];
        int d = ei[E + e];
        int pos = atomicAdd(&cursor[d], 1);
        src_sorted[pos] = s;
    }
}

// ---------------- split-bf16 conversion ----------------
// x -> [hi | lo]  (row length 2F)
__global__ __launch_bounds__(256) void convert_x_kernel(const float* __restrict__ x,
                                                        unsigned short* __restrict__ xs,
                                                        int n, int F) {
    long idx = (long)blockIdx.x * 256 + threadIdx.x;
    long total = (long)n * (F / 4);
    if (idx >= total) return;
    int row = (int)(idx / (F / 4));
    int c4 = (int)(idx % (F / 4)) * 4;
    f32x4 v = *(const f32x4*)&x[(long)row * F + c4];
    u16x4 hi, lo;
#pragma unroll
    for (int j = 0; j < 4; ++j) {
        hi[j] = f2bf(v[j]);
        lo[j] = f2bf(v[j] - bf2f(hi[j]));
    }
    unsigned short* base = xs + (long)row * 2 * F;
    *(u16x4*)&base[c4] = hi;
    *(u16x4*)&base[F + c4] = lo;
}

// W [K,N] f32 -> Wt [N, 3K] bf16 transposed: rows of B' = [hi; hi; lo]
__global__ __launch_bounds__(256) void convert_w_kernel(const float* __restrict__ W,
                                                        unsigned short* __restrict__ Wt,
                                                        int K, int N) {
    int idx = blockIdx.x * 256 + threadIdx.x;
    if (idx >= K * N) return;
    int k = idx / N, n = idx % N;
    float v = W[(long)k * N + n];
    unsigned short hi = f2bf(v);
    unsigned short lo = f2bf(v - bf2f(hi));
    unsigned short* base = Wt + (long)n * 3 * K;
    base[k] = hi;
    base[K + k] = hi;
    base[2 * K + k] = lo;
}

// ---------------- MFMA bf16 GEMM: C[M,N] = A'[M,Kp] * Bt[N,Kp]^T, epilogue *dinv[row], C in bf16 ----------------
// BM=64, BN=64, grid (M/64, N/64): many blocks -> occupancy covers barrier drains.
// A re-reads across grid.y hit L3 (panel is L3-resident). BK=64, 4 waves.
// A stored [hi|lo] (row len KA=2F); logical third segment [2F,3F) remapped to hi.
template <int BN>
__global__ __launch_bounds__(256) void gemm_bf16_kernel(const unsigned short* __restrict__ A,
                                                        const unsigned short* __restrict__ Bt,
                                                        const float* __restrict__ dinv,
                                                        unsigned short* __restrict__ C,
                                                        int M, int KA, int Kp, int N) {
    constexpr int WAVES_N = BN / 64;      // 1 for BN=64
    constexpr int WAVES_M = 4 / WAVES_N;  // 4
    constexpr int MI = 4 / WAVES_M;       // 1: one 16-row tile per wave
    constexpr int AITERS = 2;             // 512 A-chunks / 256 threads
    constexpr int BITERS = BN / 32;       // 2 for BN=64
    __shared__ short As[64 * 64];
    __shared__ short Bs[BN * 64];
    const int tid = threadIdx.x;
    const int m0 = blockIdx.x * 64;
    const int n0 = blockIdx.y * BN;
    const int wave = tid >> 6, l = tid & 63;
    const int wn = wave / WAVES_M, wm = wave % WAVES_M;
    const int lr = l & 15, lg = l >> 4;
    f32x4 acc[MI][4] = {};
    for (int k0 = 0; k0 < Kp; k0 += 64) {
#pragma unroll
        for (int it = 0; it < AITERS; ++it) {
            int chunk = it * 256 + tid;
            int mi = chunk >> 7, ks = (chunk >> 6) & 1, cl = chunk & 63;
            long row = m0 + mi * 16 + (cl & 15);
            int gk = k0 + ks * 32 + ((cl >> 4) << 3);
            if (gk >= KA) gk -= KA;       // [hi|lo|hi] logical from [hi|lo] storage
            async_copy16(&A[row * KA + gk], &As[(size_t)(it * 256 + (tid & ~63)) * 8]);
        }
#pragma unroll
        for (int it = 0; it < BITERS; ++it) {
            int chunk = it * 256 + tid;
            int ni = chunk >> 7, ks = (chunk >> 6) & 1, cl = chunk & 63;
            long col = n0 + ni * 16 + (cl & 15);
            int gk = k0 + ks * 32 + ((cl >> 4) << 3);
            async_copy16(&Bt[col * Kp + gk], &Bs[(size_t)(it * 256 + (tid & ~63)) * 8]);
        }
        __syncthreads();
#pragma unroll
        for (int ks = 0; ks < 2; ++ks) {
            short8 a[MI], b[4];
#pragma unroll
            for (int i = 0; i < MI; ++i)
                a[i] = *(const short8*)&As[(((wm * MI + i) * 2 + ks) * 64 + l) * 8];
#pragma unroll
            for (int ni = 0; ni < 4; ++ni)
                b[ni] = *(const short8*)&Bs[(((wn * 4 + ni) * 2 + ks) * 64 + l) * 8];
#pragma unroll
            for (int i = 0; i < MI; ++i)
#pragma unroll
                for (int ni = 0; ni < 4; ++ni)
                    acc[i][ni] = __builtin_amdgcn_mfma_f32_16x16x32_bf16(a[i], b[ni], acc[i][ni], 0, 0, 0);
        }
        __syncthreads();
    }
#pragma unroll
    for (int i = 0; i < MI; ++i) {
        int rbase = m0 + (wm * MI + i) * 16 + lg * 4;
#pragma unroll
        for (int ni = 0; ni < 4; ++ni) {
            int col = n0 + wn * 64 + ni * 16 + lr;
#pragma unroll
            for (int r = 0; r < 4; ++r) {
                int row = rbase + r;
                if (row < M) C[(long)row * N + col] = f2bf(acc[i][ni][r] * dinv[row]);
            }
        }
    }
}

// ---------------- bf16 gather core: 8-deep unroll, u16x8 (16B) per lane ----------------
template <int R8>   // row stride in u16x8 units
__device__ __forceinline__ f32x8 gather_sum_bf(const u16x8* __restrict__ base,
                                               const int* __restrict__ src,
                                               int beg, int end) {
    f32x8 acc = {0.f, 0.f, 0.f, 0.f, 0.f, 0.f, 0.f, 0.f};
    int e = beg;
    for (; e + 8 <= end; e += 8) {
        u16x8 v0 = base[(long)src[e] * R8],     v1 = base[(long)src[e + 1] * R8];
        u16x8 v2 = base[(long)src[e + 2] * R8], v3 = base[(long)src[e + 3] * R8];
        u16x8 v4 = base[(long)src[e + 4] * R8], v5 = base[(long)src[e + 5] * R8];
        u16x8 v6 = base[(long)src[e + 6] * R8], v7 = base[(long)src[e + 7] * R8];
        acc += ((bfv8(v0) + bfv8(v1)) + (bfv8(v2) + bfv8(v3)))
             + ((bfv8(v4) + bfv8(v5)) + (bfv8(v6) + bfv8(v7)));
    }
    for (; e < end; ++e) acc += bfv8(base[(long)src[e] * R8]);
    return acc;
}

// ---------------- f32 gather core (layers 3/4) ----------------
template <int G>
__device__ __forceinline__ f32x4 gather_sum(const f32x4* __restrict__ tsv,
                                            const int* __restrict__ src,
                                            int beg, int end, int lane) {
    f32x4 acc = {0.f, 0.f, 0.f, 0.f};
    int e = beg;
    for (; e + 8 <= end; e += 8) {
        int s0 = src[e], s1 = src[e + 1], s2 = src[e + 2], s3 = src[e + 3];
        int s4 = src[e + 4], s5 = src[e + 5], s6 = src[e + 6], s7 = src[e + 7];
        f32x4 v0 = tsv[(long)s0 * G + lane], v1 = tsv[(long)s1 * G + lane];
        f32x4 v2 = tsv[(long)s2 * G + lane], v3 = tsv[(long)s3 * G + lane];
        f32x4 v4 = tsv[(long)s4 * G + lane], v5 = tsv[(long)s5 * G + lane];
        f32x4 v6 = tsv[(long)s6 * G + lane], v7 = tsv[(long)s7 * G + lane];
        acc += ((v0 + v1) + (v2 + v3)) + ((v4 + v5) + (v6 + v7));
    }
    for (; e + 2 <= end; e += 2) {
        int s0 = src[e], s1 = src[e + 1];
        acc += tsv[(long)s0 * G + lane] + tsv[(long)s1 * G + lane];
    }
    if (e < end) acc += tsv[(long)src[e] * G + lane];
    return acc;
}

// D=256 bf16 gather: h1 = relu(dinv*sum + b1) -> split bf16 [hi|lo] write (row len 512)
__global__ __launch_bounds__(256) void agg_split256_kernel(const unsigned short* __restrict__ ts,
                                                           const int* __restrict__ row_ptr,
                                                           const int* __restrict__ src_sorted,
                                                           const float* __restrict__ dinv,
                                                           const float* __restrict__ bias,
                                                           unsigned short* __restrict__ out_s,
                                                           int n) {
    int g = threadIdx.x >> 5, lane = threadIdx.x & 31;   // 8 nodes/block, 32 lanes/node
    int node = blockIdx.x * 8 + g;
    if (node >= n) return;
    const u16x8* base = (const u16x8*)ts + lane;         // row stride 32 chunks
    f32x8 acc = gather_sum_bf<32>(base, src_sorted, row_ptr[node], row_ptr[node + 1]);
    float di = dinv[node];
    f32x8 b8 = *(const f32x8*)&bias[lane * 8];
    f32x8 v = acc * di + b8;
    u16x8 hi, lo;
#pragma unroll
    for (int j = 0; j < 8; ++j) {
        float r = fmaxf(v[j], 0.f);
        hi[j] = f2bf(r);
        lo[j] = f2bf(r - bf2f(hi[j]));
    }
    unsigned short* ob = out_s + (long)node * 512 + lane * 8;
    *(u16x8*)ob = hi;
    *(u16x8*)(ob + 256) = lo;
}

// D=128 bf16 gather + fused W3 matvec: ts3[node] = dinv * (relu(dinv*sum+b2) @ W3)  (128 -> 32)
__global__ __launch_bounds__(256) void agg_fused_w3_kernel(const unsigned short* __restrict__ ts,
                                                           const int* __restrict__ row_ptr,
                                                           const int* __restrict__ src_sorted,
                                                           const float* __restrict__ dinv,
                                                           const float* __restrict__ bias,
                                                           const float* __restrict__ W3,
                                                           float* __restrict__ ts3, int n) {
    __shared__ float W3s[128 * 32];
    __shared__ float hbuf[16][132];   // +4 pad: spreads per-node broadcast reads across banks
    for (int i = threadIdx.x; i < 128 * 32; i += 256) W3s[i] = W3[i];
    __syncthreads();
    int g = threadIdx.x >> 4, lane = threadIdx.x & 15;   // 16 nodes/block, 16 lanes/node
    int node = blockIdx.x * 16 + g;
    if (node >= n) return;
    const u16x8* base = (const u16x8*)ts + lane;         // row stride 16 chunks
    f32x8 acc = gather_sum_bf<16>(base, src_sorted, row_ptr[node], row_ptr[node + 1]);
    float di = dinv[node];
    f32x8 b8 = *(const f32x8*)&bias[lane * 8];
    f32x8 v = acc * di + b8;
#pragma unroll
    for (int j = 0; j < 8; ++j) v[j] = fmaxf(v[j], 0.f);
    f32x4 vlo = {v[0], v[1], v[2], v[3]};
    f32x4 vhi = {v[4], v[5], v[6], v[7]};
    *(f32x4*)&hbuf[g][lane * 8] = vlo;        // same-wave DS: in-order, no barrier needed
    *(f32x4*)&hbuf[g][lane * 8 + 4] = vhi;
    int c0 = lane * 2;
    float aj0 = 0.f, aj1 = 0.f;
#pragma unroll
    for (int k = 0; k < 128; k += 4) {
        f32x4 hv = *(const f32x4*)&hbuf[g][k];
        aj0 += hv[0] * W3s[k * 32 + c0] + hv[1] * W3s[(k + 1) * 32 + c0]
             + hv[2] * W3s[(k + 2) * 32 + c0] + hv[3] * W3s[(k + 3) * 32 + c0];
        aj1 += hv[0] * W3s[k * 32 + c0 + 1] + hv[1] * W3s[(k + 1) * 32 + c0 + 1]
             + hv[2] * W3s[(k + 2) * 32 + c0 + 1] + hv[3] * W3s[(k + 3) * 32 + c0 + 1];
    }
    f32x2 o = {aj0 * di, aj1 * di};
    *(f32x2*)&ts3[(long)node * 32 + c0] = o;
}

// D=32 agg + fused Wk matvec: tsk[node] = dinv * (relu(dinv*sum+b3) @ Wk)    (32 -> 8)
__global__ __launch_bounds__(256) void agg_fused_wk_kernel(const float* __restrict__ ts,
                                                           const int* __restrict__ row_ptr,
                                                           const int* __restrict__ src_sorted,
                                                           const float* __restrict__ dinv,
                                                           const float* __restrict__ bias,
                                                           const float* __restrict__ Wk,
                                                           float* __restrict__ tsk, int n) {
    __shared__ float Wks[32 * 8];
    __shared__ float hbuf[32][36];   // +4 pad
    for (int i = threadIdx.x; i < 32 * 8; i += 256) Wks[i] = Wk[i];
    __syncthreads();
    int g = threadIdx.x >> 3, lane = threadIdx.x & 7;
    int node = blockIdx.x * 32 + g;
    if (node >= n) return;
    f32x4 acc = gather_sum<8>((const f32x4*)ts, src_sorted, row_ptr[node], row_ptr[node + 1], lane);
    float di = dinv[node];
    f32x4 b4 = *(const f32x4*)&bias[lane * 4];
    f32x4 v = acc * di + b4;
#pragma unroll
    for (int j = 0; j < 4; ++j) v[j] = fmaxf(v[j], 0.f);
    *(f32x4*)&hbuf[g][lane * 4] = v;
    float aj = 0.f;
#pragma unroll
    for (int k = 0; k < 32; k += 4) {
        f32x4 hv = *(const f32x4*)&hbuf[g][k];
        aj += hv[0] * Wks[k * 8 + lane] + hv[1] * Wks[(k + 1) * 8 + lane]
            + hv[2] * Wks[(k + 2) * 8 + lane] + hv[3] * Wks[(k + 3) * 8 + lane];
    }
    tsk[(long)node * 8 + lane] = aj * di;
}

// D=8: z = relu(dinv*sum + bk)
__global__ __launch_bounds__(256) void agg_plain8_kernel(const float* __restrict__ ts,
                                                         const int* __restrict__ row_ptr,
                                                         const int* __restrict__ src_sorted,
                                                         const float* __restrict__ dinv,
                                                         const float* __restrict__ bias,
                                                         float* __restrict__ z, int n) {
    int g = threadIdx.x >> 1, lane = threadIdx.x & 1;
    int node = blockIdx.x * 128 + g;
    if (node >= n) return;
    f32x4 acc = gather_sum<2>((const f32x4*)ts, src_sorted, row_ptr[node], row_ptr[node + 1], lane);
    float di = dinv[node];
    f32x4 b4 = *(const f32x4*)&bias[lane * 4];
    f32x4 v = acc * di + b4;
#pragma unroll
    for (int j = 0; j < 4; ++j) v[j] = fmaxf(v[j], 0.f);
    *(f32x4*)&z[(long)node * 8 + lane * 4] = v;
}

// ---------------- decoder: out[k,e] = dot(z[s_e], z[d_e]) (identical across k) ----------------
__global__ __launch_bounds__(256) void decoder_kernel(const float* __restrict__ z,
                                                      const int* __restrict__ ei,
                                                      float* __restrict__ out,
                                                      int E, int K) {
    int e = blockIdx.x * blockDim.x + threadIdx.x;
    if (e >= E) return;
    int s = ei[e];
    int d = ei[E + e];
    const f32x4* zv = (const f32x4*)z;
    f32x4 a0 = zv[(long)s * 2], a1 = zv[(long)s * 2 + 1];
    f32x4 b0 = zv[(long)d * 2], b1 = zv[(long)d * 2 + 1];
    f32x4 p = a0 * b0 + a1 * b1;
    float acc = p[0] + p[1] + p[2] + p[3];
    for (int k = 0; k < K; k++) out[(long)k * E + e] = acc;
}

// ---------------- launch ----------------

extern "C" void kernel_launch(void* const* d_in, const int* in_sizes, int n_in,
                              void* d_out, int out_size, void* d_ws, size_t ws_size,
                              hipStream_t stream) {
    const float* x  = (const float*)d_in[0];
    const int*   ei = (const int*)d_in[1];
    const float* W1 = (const float*)d_in[3];
    const float* b1 = (const float*)d_in[4];
    const float* W2 = (const float*)d_in[5];
    const float* b2 = (const float*)d_in[6];
    const float* W3 = (const float*)d_in[7];
    const float* b3 = (const float*)d_in[8];
    const float* Wk = (const float*)d_in[9];
    const float* bk = (const float*)d_in[10];
    float* out = (float*)d_out;

    const int D1 = in_sizes[4];            // 256
    const int D2 = in_sizes[6];            // 128
    const int F  = in_sizes[3] / D1;       // 256
    const int N  = in_sizes[0] / F;        // 50000
    const int E  = in_sizes[1] / 2;        // 800000
    const int K  = out_size / E;           // 8
    const int M  = E + N;                  // edges incl self loops
    const int Mpad = (N + 127) & ~127;     // 50048

    size_t off = 0;
    auto alloc = [&](size_t bytes) -> void* {
        off = (off + 255) & ~(size_t)255;
        void* p = (char*)d_ws + off;
        off += bytes;
        return p;
    };
    int*   cnt        = (int*)alloc((size_t)N * sizeof(int));
    int*   row_ptr    = (int*)alloc((size_t)(N + 1) * sizeof(int));
    int*   cursor     = (int*)alloc((size_t)N * sizeof(int));
    float* dinv       = (float*)alloc((size_t)N * sizeof(float));
    int*   src_sorted = (int*)alloc((size_t)M * sizeof(int));
    unsigned short* region_x = (unsigned short*)alloc((size_t)Mpad * 2 * F * sizeof(short));  // xs -> h1s (51.2MB)
    float* region_t   = (float*)alloc((size_t)Mpad * 256 * sizeof(float));                    // ts1/ts2 (as bf16)
    unsigned short* Wt1 = (unsigned short*)alloc((size_t)D1 * 3 * F * sizeof(short));
    unsigned short* Wt2 = (unsigned short*)alloc((size_t)D2 * 3 * D1 * sizeof(short));
    float* ts3        = (float*)alloc((size_t)Mpad * 32 * sizeof(float));
    float* tsk        = (float*)alloc((size_t)Mpad * 8 * sizeof(float));
    float* z          = (float*)alloc((size_t)Mpad * 8 * sizeof(float));
    (void)ws_size; (void)n_in;

    unsigned short* xs  = region_x;
    unsigned short* h1s = region_x;                 // reused after GEMM1 consumed xs
    unsigned short* ts1 = (unsigned short*)region_t;  // [Mpad,256] bf16 (25.6MB)
    unsigned short* ts2 = (unsigned short*)region_t;  // [Mpad,128] bf16 (ts1 consumed)

    int nbN = (N + THREADS - 1) / THREADS;
    int nbE = (E + THREADS - 1) / THREADS;

    // ---- graph prep ----
    init_cnt_kernel<<<nbN, THREADS, 0, stream>>>(cnt, N);
    count_edges_kernel<<<nbE, THREADS, 0, stream>>>(ei, cnt, E);
    scan_kernel<<<1, 1024, 0, stream>>>(cnt, row_ptr, N);
    prep_fused_kernel<<<nbN, THREADS, 0, stream>>>(cnt, row_ptr, cursor, dinv, src_sorted, N);
    fill_edges_kernel<<<nbE, THREADS, 0, stream>>>(ei, cursor, src_sorted, E);

    // ---- conversions ----
    convert_x_kernel<<<(int)(((long)N * (F / 4) + 255) / 256), THREADS, 0, stream>>>(x, xs, N, F);
    convert_w_kernel<<<(F * D1 + 255) / 256, THREADS, 0, stream>>>(W1, Wt1, F, D1);
    convert_w_kernel<<<(D1 * D2 + 255) / 256, THREADS, 0, stream>>>(W2, Wt2, D1, D2);

    // ---- layer 1: ts1 = bf16(dinv .* (x @ W1)); agg (bf16 gather) -> h1s [hi|lo] ----
    gemm_bf16_kernel<64><<<dim3(Mpad / 64, D1 / 64), THREADS, 0, stream>>>(xs, Wt1, dinv, ts1, N, 2 * F, 3 * F, D1);
    agg_split256_kernel<<<(N + 7) / 8, THREADS, 0, stream>>>(ts1, row_ptr, src_sorted, dinv, b1, h1s, N);

    // ---- layer 2: ts2 = bf16(dinv .* (h1 @ W2)); agg (bf16 gather) + fused W3 -> ts3 ----
    gemm_bf16_kernel<64><<<dim3(Mpad / 64, D2 / 64), THREADS, 0, stream>>>(h1s, Wt2, dinv, ts2, N, 2 * D1, 3 * D1, D2);
    agg_fused_w3_kernel<<<(N + 15) / 16, THREADS, 0, stream>>>(ts2, row_ptr, src_sorted, dinv, b2, W3, ts3, N);

    // ---- layer 3 agg + fused Wk (32 -> 8), then final agg ----
    agg_fused_wk_kernel<<<(N + 31) / 32, THREADS, 0, stream>>>(ts3, row_ptr, src_sorted, dinv, b3, Wk, tsk, N);
    agg_plain8_kernel<<<(N + 127) / 128, THREADS, 0, stream>>>(tsk, row_ptr, src_sorted, dinv, bk, z, N);

    // ---- decoder ----
    decoder_kernel<<<nbE, THREADS, 0, stream>>>(z, ei, out, E, K);
}